// Round 1
// baseline (239.527 us; speedup 1.0000x reference)
//
#include <hip/hip_runtime.h>

#define N_NODES 50000
#define IN_DIM 128
#define OUT_DIM 128

// ---------------- Kernel 0: out[m][:] = b ----------------
__global__ void bias_init_kernel(const float* __restrict__ b, float* __restrict__ out, int n4) {
    int i = blockIdx.x * blockDim.x + threadIdx.x;
    if (i < n4) {
        const float4* b4 = (const float4*)b;   // 128 floats = 32 float4
        ((float4*)out)[i] = b4[i & 31];
    }
}

// ---------------- Kernel 1: T = H @ W  (M x 128 @ 128 x 128, fp32) ----------------
// Block: 256 threads, computes 32 rows x 128 cols. Thread tile 4x4.
__global__ __launch_bounds__(256) void gemm_kernel(const float* __restrict__ H,
                                                   const float* __restrict__ W,
                                                   float* __restrict__ T, int M) {
    __shared__ float As[32][64];    // 8 KB  (k-chunk of A)
    __shared__ float Ws[64][128];   // 32 KB (k-chunk of W)

    const int tid = threadIdx.x;
    const int row0 = blockIdx.x * 32;
    const int rr = tid >> 5;        // 0..7  -> rows rr*4 + i
    const int cc = tid & 31;        // 0..31 -> cols cc*4 + j

    float acc[4][4];
#pragma unroll
    for (int i = 0; i < 4; ++i)
#pragma unroll
        for (int j = 0; j < 4; ++j) acc[i][j] = 0.f;

    for (int kc = 0; kc < 128; kc += 64) {
        // Load A chunk: 32 rows x 64 cols = 512 float4, 2 per thread
#pragma unroll
        for (int f = tid; f < 512; f += 256) {
            int r = f >> 4, c = (f & 15) << 2;
            int gr = row0 + r;
            float4 v = make_float4(0.f, 0.f, 0.f, 0.f);
            if (gr < M) v = *(const float4*)&H[gr * 128 + kc + c];
            *(float4*)&As[r][c] = v;
        }
        // Load W chunk: 64 rows x 128 cols = 2048 float4, 8 per thread
#pragma unroll
        for (int f = tid; f < 2048; f += 256) {
            int r = f >> 5, c = (f & 31) << 2;
            *(float4*)&Ws[r][c] = *(const float4*)&W[(kc + r) * 128 + c];
        }
        __syncthreads();

#pragma unroll
        for (int k = 0; k < 64; k += 4) {
            float4 a[4], w[4];
#pragma unroll
            for (int i = 0; i < 4; ++i) a[i] = *(const float4*)&As[rr * 4 + i][k];
#pragma unroll
            for (int j = 0; j < 4; ++j) w[j] = *(const float4*)&Ws[k + j][cc * 4];
#pragma unroll
            for (int i = 0; i < 4; ++i) {
                acc[i][0] += a[i].x * w[0].x; acc[i][1] += a[i].x * w[0].y;
                acc[i][2] += a[i].x * w[0].z; acc[i][3] += a[i].x * w[0].w;
                acc[i][0] += a[i].y * w[1].x; acc[i][1] += a[i].y * w[1].y;
                acc[i][2] += a[i].y * w[1].z; acc[i][3] += a[i].y * w[1].w;
                acc[i][0] += a[i].z * w[2].x; acc[i][1] += a[i].z * w[2].y;
                acc[i][2] += a[i].z * w[2].z; acc[i][3] += a[i].z * w[2].w;
                acc[i][0] += a[i].w * w[3].x; acc[i][1] += a[i].w * w[3].y;
                acc[i][2] += a[i].w * w[3].z; acc[i][3] += a[i].w * w[3].w;
            }
        }
        __syncthreads();
    }

#pragma unroll
    for (int i = 0; i < 4; ++i) {
        int gr = row0 + rr * 4 + i;
        if (gr < M) {
            float4 v = make_float4(acc[i][0], acc[i][1], acc[i][2], acc[i][3]);
            *(float4*)&T[gr * 128 + cc * 4] = v;
        }
    }
}

// ---------------- Kernel 2: out[dst] += w * T[src]  (dst sorted) ----------------
// Block: 256 threads = 4 waves; each wave handles 256 contiguous edges.
// Lane owns 2 feature columns (float2). Segmented accumulate in registers,
// flush with atomicAdd only on dst change (wave-uniform branch).
__global__ __launch_bounds__(256) void scatter_kernel(const float* __restrict__ T,
                                                      const int* __restrict__ esrc,
                                                      const int* __restrict__ edst,
                                                      const float* __restrict__ ew,
                                                      float* __restrict__ out, int E) {
    __shared__ int s_src[1024];
    __shared__ int s_dst[1024];
    __shared__ float s_w[1024];

    const int tid = threadIdx.x;
    const int e0 = blockIdx.x * 1024;

#pragma unroll
    for (int i = tid; i < 1024; i += 256) {
        int e = e0 + i;
        if (e < E) {
            s_src[i] = esrc[e];
            s_dst[i] = edst[e];
            s_w[i] = ew[e];
        } else {
            s_dst[i] = -1;
        }
    }
    __syncthreads();

    const int wave = tid >> 6;
    const int lane = tid & 63;
    const int base = wave << 8;          // 256 edges per wave
    const int col = lane << 1;

    int nloc = E - (e0 + base);
    if (nloc > 256) nloc = 256;

    float ax = 0.f, ay = 0.f;
    int prev = -1;
    for (int i = 0; i < nloc; ++i) {
        int d = s_dst[base + i];          // wave-uniform
        if (d != prev) {                  // wave-uniform branch
            if (prev >= 0) {
                atomicAdd(&out[prev * 128 + col], ax);
                atomicAdd(&out[prev * 128 + col + 1], ay);
            }
            ax = 0.f; ay = 0.f;
            prev = d;
        }
        float wt = s_w[base + i];
        const float2 v = *(const float2*)&T[s_src[base + i] * 128 + col];
        ax += wt * v.x;
        ay += wt * v.y;
    }
    if (prev >= 0) {
        atomicAdd(&out[prev * 128 + col], ax);
        atomicAdd(&out[prev * 128 + col + 1], ay);
    }
}

extern "C" void kernel_launch(void* const* d_in, const int* in_sizes, int n_in,
                              void* d_out, int out_size, void* d_ws, size_t ws_size,
                              hipStream_t stream) {
    const float* H    = (const float*)d_in[0];
    const int*   esrc = (const int*)d_in[1];
    const int*   edst = (const int*)d_in[2];
    const float* ew   = (const float*)d_in[3];
    const float* W    = (const float*)d_in[4];
    const float* b    = (const float*)d_in[5];
    float* out = (float*)d_out;
    float* T   = (float*)d_ws;   // 50000*128*4 = 25.6 MB scratch

    const int M = in_sizes[0] / IN_DIM;   // 50000
    const int E = in_sizes[1];            // 1,600,000

    // out[m][:] = b
    int n4 = M * OUT_DIM / 4;
    bias_init_kernel<<<(n4 + 255) / 256, 256, 0, stream>>>(b, out, n4);

    // T = H @ W
    gemm_kernel<<<(M + 31) / 32, 256, 0, stream>>>(H, W, T, M);

    // out[dst] += w * T[src]
    scatter_kernel<<<(E + 1023) / 1024, 256, 0, stream>>>(T, esrc, edst, ew, out, E);
}

// Round 2
// 188.679 us; speedup vs baseline: 1.2695x; 1.2695x over previous
//
#include <hip/hip_runtime.h>
#include <hip/hip_bf16.h>

#define IN_DIM 128
#define OUT_DIM 128

typedef __attribute__((ext_vector_type(8))) short short8;

__device__ __forceinline__ ushort f2bf(float f) {
    unsigned int u = __builtin_bit_cast(unsigned int, f);
    unsigned int r = (u + 0x7fffu + ((u >> 16) & 1u)) >> 16;   // RNE
    return (ushort)r;
}

// ---------------- Kernel 0: out[m][:] = b ----------------
__global__ void bias_init_kernel(const float* __restrict__ b, float* __restrict__ out, int n4) {
    int i = blockIdx.x * blockDim.x + threadIdx.x;
    if (i < n4) {
        const float4* b4 = (const float4*)b;   // 128 floats = 32 float4
        ((float4*)out)[i] = b4[i & 31];
    }
}

// ---------------- Kernel 1: T(bf16) = H @ W  (M x 128 @ 128 x 128) ----------------
// Block 256 threads -> 128-row x 128-col tile; thread tile 8x8.
// Rows per thread interleaved stride-16 so A-frag LDS reads are conflict-free
// (bank offset = 36*ty mod 32 = 4*ty for ty=0..3 within a wave).
__global__ __launch_bounds__(256) void gemm_kernel(const float* __restrict__ H,
                                                   const float* __restrict__ W,
                                                   ushort* __restrict__ T, int M) {
    __shared__ float As[128][36];    // 18 KB, padded
    __shared__ float Ws[32][132];    // 16.5 KB, padded (row stride 528 B, 16B-aligned)

    const int tid = threadIdx.x;
    const int row0 = blockIdx.x * 128;
    const int tx = tid & 15;         // col group: cols tx*8 .. +8
    const int ty = tid >> 4;         // row group: rows ty + 16*i, i=0..7

    float acc[8][8];
#pragma unroll
    for (int i = 0; i < 8; ++i)
#pragma unroll
        for (int j = 0; j < 8; ++j) acc[i][j] = 0.f;

    for (int kc = 0; kc < 128; kc += 32) {
        // Stage A chunk: 128 rows x 32 k = 1024 float4
#pragma unroll
        for (int f = tid; f < 1024; f += 256) {
            int r = f >> 3, c4 = (f & 7) << 2;
            int gr = row0 + r;
            float4 v = make_float4(0.f, 0.f, 0.f, 0.f);
            if (gr < M) v = *(const float4*)&H[gr * 128 + kc + c4];
            *(float4*)&As[r][c4] = v;
        }
        // Stage W chunk: 32 k x 128 cols = 1024 float4
#pragma unroll
        for (int f = tid; f < 1024; f += 256) {
            int kr = f >> 5, c4 = (f & 31) << 2;
            *(float4*)&Ws[kr][c4] = *(const float4*)&W[(kc + kr) * 128 + c4];
        }
        __syncthreads();

#pragma unroll
        for (int kk = 0; kk < 32; kk += 4) {
            float4 a[8], w0[4], w1[4];
#pragma unroll
            for (int i = 0; i < 8; ++i) a[i] = *(const float4*)&As[ty + 16 * i][kk];
#pragma unroll
            for (int j = 0; j < 4; ++j) {
                w0[j] = *(const float4*)&Ws[kk + j][tx * 8];
                w1[j] = *(const float4*)&Ws[kk + j][tx * 8 + 4];
            }
#pragma unroll
            for (int i = 0; i < 8; ++i) {
                acc[i][0] += a[i].x * w0[0].x; acc[i][1] += a[i].x * w0[0].y;
                acc[i][2] += a[i].x * w0[0].z; acc[i][3] += a[i].x * w0[0].w;
                acc[i][4] += a[i].x * w1[0].x; acc[i][5] += a[i].x * w1[0].y;
                acc[i][6] += a[i].x * w1[0].z; acc[i][7] += a[i].x * w1[0].w;

                acc[i][0] += a[i].y * w0[1].x; acc[i][1] += a[i].y * w0[1].y;
                acc[i][2] += a[i].y * w0[1].z; acc[i][3] += a[i].y * w0[1].w;
                acc[i][4] += a[i].y * w1[1].x; acc[i][5] += a[i].y * w1[1].y;
                acc[i][6] += a[i].y * w1[1].z; acc[i][7] += a[i].y * w1[1].w;

                acc[i][0] += a[i].z * w0[2].x; acc[i][1] += a[i].z * w0[2].y;
                acc[i][2] += a[i].z * w0[2].z; acc[i][3] += a[i].z * w0[2].w;
                acc[i][4] += a[i].z * w1[2].x; acc[i][5] += a[i].z * w1[2].y;
                acc[i][6] += a[i].z * w1[2].z; acc[i][7] += a[i].z * w1[2].w;

                acc[i][0] += a[i].w * w0[3].x; acc[i][1] += a[i].w * w0[3].y;
                acc[i][2] += a[i].w * w0[3].z; acc[i][3] += a[i].w * w0[3].w;
                acc[i][4] += a[i].w * w1[3].x; acc[i][5] += a[i].w * w1[3].y;
                acc[i][6] += a[i].w * w1[3].z; acc[i][7] += a[i].w * w1[3].w;
            }
        }
        __syncthreads();
    }

    // Epilogue: pack to bf16, one 16B store per row
#pragma unroll
    for (int i = 0; i < 8; ++i) {
        int gr = row0 + ty + 16 * i;
        if (gr < M) {
            short8 o;
#pragma unroll
            for (int j = 0; j < 8; ++j) o[j] = (short)f2bf(acc[i][j]);
            *(short8*)&T[gr * 128 + tx * 8] = o;
        }
    }
}

// ---------------- Kernel 2: out[dst] += w * T[src]  (dst sorted, T bf16) ----------------
// 256 threads = 4 waves; wave handles 256 contiguous edges; lane owns 2 cols.
// Batch-16 gather loads for MLP; register segment-accumulate, atomic flush on
// dst change (wave-uniform branch).
__global__ __launch_bounds__(256) void scatter_kernel(const unsigned int* __restrict__ T2,
                                                      const int* __restrict__ esrc,
                                                      const int* __restrict__ edst,
                                                      const float* __restrict__ ew,
                                                      float* __restrict__ out, int E) {
    __shared__ int s_src[1024];
    __shared__ int s_dst[1024];
    __shared__ float s_w[1024];

    const int tid = threadIdx.x;
    const int e0 = blockIdx.x * 1024;

#pragma unroll
    for (int i = tid; i < 1024; i += 256) {
        int e = e0 + i;
        if (e < E) {
            s_src[i] = esrc[e];
            s_dst[i] = edst[e];
            s_w[i] = ew[e];
        } else {
            s_src[i] = 0;
            s_dst[i] = -1;
            s_w[i] = 0.f;
        }
    }
    __syncthreads();

    const int wave = tid >> 6;
    const int lane = tid & 63;
    const int base = wave << 8;
    const int col = lane << 1;

    float ax = 0.f, ay = 0.f;
    int prev = -1;

    for (int i0 = 0; i0 < 256; i0 += 16) {
        unsigned int v[16];
        float wt[16];
        int d[16];
#pragma unroll
        for (int j = 0; j < 16; ++j) {
            int ii = base + i0 + j;
            d[j] = s_dst[ii];
            wt[j] = s_w[ii];
            v[j] = T2[(unsigned int)s_src[ii] * 64u + (unsigned int)lane];
        }
#pragma unroll
        for (int j = 0; j < 16; ++j) {
            if (d[j] != prev) {                 // wave-uniform branch
                if (prev >= 0) {
                    atomicAdd(&out[prev * 128 + col], ax);
                    atomicAdd(&out[prev * 128 + col + 1], ay);
                }
                ax = 0.f; ay = 0.f;
                prev = d[j];
            }
            float fx = __builtin_bit_cast(float, v[j] << 16);
            float fy = __builtin_bit_cast(float, v[j] & 0xffff0000u);
            ax += wt[j] * fx;
            ay += wt[j] * fy;
        }
    }
    if (prev >= 0) {
        atomicAdd(&out[prev * 128 + col], ax);
        atomicAdd(&out[prev * 128 + col + 1], ay);
    }
}

extern "C" void kernel_launch(void* const* d_in, const int* in_sizes, int n_in,
                              void* d_out, int out_size, void* d_ws, size_t ws_size,
                              hipStream_t stream) {
    const float* H    = (const float*)d_in[0];
    const int*   esrc = (const int*)d_in[1];
    const int*   edst = (const int*)d_in[2];
    const float* ew   = (const float*)d_in[3];
    const float* W    = (const float*)d_in[4];
    const float* b    = (const float*)d_in[5];
    float* out = (float*)d_out;
    ushort* T  = (ushort*)d_ws;     // 50000*128*2 = 12.8 MB scratch (bf16)

    const int M = in_sizes[0] / IN_DIM;   // 50000
    const int E = in_sizes[1];            // 1,600,000

    int n4 = M * OUT_DIM / 4;
    bias_init_kernel<<<(n4 + 255) / 256, 256, 0, stream>>>(b, out, n4);

    gemm_kernel<<<(M + 127) / 128, 256, 0, stream>>>(H, W, T, M);

    scatter_kernel<<<(E + 1023) / 1024, 256, 0, stream>>>((const unsigned int*)T, esrc, edst, ew, out, E);
}

// Round 3
// 160.642 us; speedup vs baseline: 1.4911x; 1.1745x over previous
//
#include <hip/hip_runtime.h>

#define IN_DIM 128
#define OUT_DIM 128

typedef __attribute__((ext_vector_type(8))) short short8v;   // 8 bf16 = 4 VGPRs
typedef __attribute__((ext_vector_type(4))) short short4v;   // 4 bf16 = 2 VGPRs
typedef __attribute__((ext_vector_type(4))) float float4v;

__device__ __forceinline__ ushort f2bf(float f) {
    unsigned int u = __builtin_bit_cast(unsigned int, f);
    unsigned int r = (u + 0x7fffu + ((u >> 16) & 1u)) >> 16;   // RNE
    return (ushort)r;
}
__device__ __forceinline__ float bflo(unsigned int v) {
    return __builtin_bit_cast(float, v << 16);
}
__device__ __forceinline__ float bfhi(unsigned int v) {
    return __builtin_bit_cast(float, v & 0xffff0000u);
}

// ---------------- Kernel 0: prep ----------------
// blocks [0, nb_rp): row_ptr[n] = lower_bound(edst, n)   (edst sorted)
// blocks [nb_rp, nb_rp+16): Wt_bf16[n][k] = bf16(W[k][n]), row stride 136
__global__ __launch_bounds__(256) void prep_kernel(const int* __restrict__ edst,
                                                   int* __restrict__ rp,
                                                   const float* __restrict__ W,
                                                   ushort* __restrict__ Wt,
                                                   int E, int N, int nb_rp) {
    int bid = blockIdx.x;
    if (bid < nb_rp) {
        int n = bid * 256 + threadIdx.x;
        if (n <= N) {
            int lo = 0, hi = E;
            while (lo < hi) {
                int mid = (lo + hi) >> 1;
                if (edst[mid] < n) lo = mid + 1; else hi = mid;
            }
            rp[n] = lo;
        }
    } else {
        int t = threadIdx.x;
        int k0 = (bid - nb_rp) * 8;
        int w = t >> 6, lane = t & 63;
#pragma unroll
        for (int i = 0; i < 2; ++i) {
            int k = k0 + i * 4 + w;
            int n = lane * 2;
            float2 v = *(const float2*)&W[k * 128 + n];
            Wt[n * 136 + k] = f2bf(v.x);
            Wt[(n + 1) * 136 + k] = f2bf(v.y);
        }
    }
}

// ---------------- Kernel 1: T(bf16) = H @ W via MFMA ----------------
// Block 256 thr = 4 waves; 64-row x 128-col tile, K=128 in one stage.
// Wave w computes rows [w*16, w*16+16). Per 16x16 block: a = Wt-frag (i=n),
// b = H-frag (j=m)  ->  D[n][m]: C-layout col(lane&15)=m, row(quad*4+reg)=n
// => lane holds 4 consecutive n of one row m: 8 B packed store.
__global__ __launch_bounds__(256) void gemm_kernel(const float* __restrict__ H,
                                                   const ushort* __restrict__ Wt_g,
                                                   ushort* __restrict__ T, int M) {
    __shared__ ushort Hs[64 * 136];    // 17408 B
    __shared__ ushort Ws[128 * 136];   // 34816 B

    const int t = threadIdx.x;
    const int row0 = blockIdx.x * 64;

    // Stage Ws: flat b128 copy (pad bytes copied too, never read by frags)
#pragma unroll
    for (int f = t; f < 2176; f += 256)
        ((short8v*)Ws)[f] = ((const short8v*)Wt_g)[f];

    // Stage Hs: per inst a wave covers 2 full rows (1024 B contiguous)
#pragma unroll
    for (int i = 0; i < 8; ++i) {
        int r = i * 8 + (t >> 5);
        int c4 = (t & 31) * 4;
        int gr = row0 + r;
        float4 v = make_float4(0.f, 0.f, 0.f, 0.f);
        if (gr < M) v = *(const float4*)&H[gr * 128 + c4];
        short4v o = { (short)f2bf(v.x), (short)f2bf(v.y), (short)f2bf(v.z), (short)f2bf(v.w) };
        *(short4v*)&Hs[r * 136 + c4] = o;
    }
    __syncthreads();

    const int w = t >> 6;
    const int l = t & 63;
    const int m16 = l & 15;
    const int kq = (l >> 4) * 8;

    float4v acc[8];
#pragma unroll
    for (int nt = 0; nt < 8; ++nt) acc[nt] = (float4v){0.f, 0.f, 0.f, 0.f};

#pragma unroll
    for (int ks = 0; ks < 4; ++ks) {
        short8v bfrag = *(const short8v*)&Hs[(w * 16 + m16) * 136 + ks * 32 + kq];
#pragma unroll
        for (int nt = 0; nt < 8; ++nt) {
            short8v afrag = *(const short8v*)&Ws[(nt * 16 + m16) * 136 + ks * 32 + kq];
            acc[nt] = __builtin_amdgcn_mfma_f32_16x16x32_bf16(afrag, bfrag, acc[nt], 0, 0, 0);
        }
    }

    const int gr = row0 + w * 16 + m16;
    if (gr < M) {
        const int q4 = (l >> 4) * 4;
#pragma unroll
        for (int nt = 0; nt < 8; ++nt) {
            short4v o = { (short)f2bf(acc[nt][0]), (short)f2bf(acc[nt][1]),
                          (short)f2bf(acc[nt][2]), (short)f2bf(acc[nt][3]) };
            *(short4v*)&T[gr * 128 + nt * 16 + q4] = o;
        }
    }
}

// ---------------- Kernel 2: out[n][:] = b + sum_{e in seg(n)} w_e * T[src_e][:] ----------------
// One wave per node (dst sorted => contiguous segment via row_ptr).
// Lane owns 2 cols (one dword of bf16 T row). Edge meta vector-loaded once
// per 64-edge chunk, broadcast via readlane. Direct store, no atomics.
__global__ __launch_bounds__(256) void scatter_kernel(const unsigned int* __restrict__ T2,
                                                      const int* __restrict__ esrc,
                                                      const float* __restrict__ ew,
                                                      const int* __restrict__ rp,
                                                      const float* __restrict__ b,
                                                      float* __restrict__ out) {
    const int node = blockIdx.x * 4 + (threadIdx.x >> 6);
    const int lane = threadIdx.x & 63;

    const int s = rp[node];
    const int e = rp[node + 1];

    float2 bias = *(const float2*)&b[lane * 2];
    float ax = bias.x, ay = bias.y;

    for (int c = s; c < e; c += 64) {
        int idx = c + lane;
        int srcl = 0;
        float wl = 0.f;
        if (idx < e) { srcl = esrc[idx]; wl = ew[idx]; }
        int nn = e - c;
        if (nn > 64) nn = 64;
        int wli = __builtin_bit_cast(int, wl);
        for (int j = 0; j < nn; j += 4) {
            int s0 = __builtin_amdgcn_readlane(srcl, j + 0);
            int s1 = __builtin_amdgcn_readlane(srcl, j + 1);
            int s2 = __builtin_amdgcn_readlane(srcl, j + 2);
            int s3 = __builtin_amdgcn_readlane(srcl, j + 3);
            float w0 = __builtin_bit_cast(float, __builtin_amdgcn_readlane(wli, j + 0));
            float w1 = __builtin_bit_cast(float, __builtin_amdgcn_readlane(wli, j + 1));
            float w2 = __builtin_bit_cast(float, __builtin_amdgcn_readlane(wli, j + 2));
            float w3 = __builtin_bit_cast(float, __builtin_amdgcn_readlane(wli, j + 3));
            unsigned int v0 = T2[(unsigned int)s0 * 64u + (unsigned int)lane];
            unsigned int v1 = T2[(unsigned int)s1 * 64u + (unsigned int)lane];
            unsigned int v2 = T2[(unsigned int)s2 * 64u + (unsigned int)lane];
            unsigned int v3 = T2[(unsigned int)s3 * 64u + (unsigned int)lane];
            ax += w0 * bflo(v0); ay += w0 * bfhi(v0);
            ax += w1 * bflo(v1); ay += w1 * bfhi(v1);
            ax += w2 * bflo(v2); ay += w2 * bfhi(v2);
            ax += w3 * bflo(v3); ay += w3 * bfhi(v3);
        }
    }

    float2 o = make_float2(ax, ay);
    *(float2*)&out[node * 128 + lane * 2] = o;
}

extern "C" void kernel_launch(void* const* d_in, const int* in_sizes, int n_in,
                              void* d_out, int out_size, void* d_ws, size_t ws_size,
                              hipStream_t stream) {
    const float* H    = (const float*)d_in[0];
    const int*   esrc = (const int*)d_in[1];
    const int*   edst = (const int*)d_in[2];
    const float* ew   = (const float*)d_in[3];
    const float* W    = (const float*)d_in[4];
    const float* b    = (const float*)d_in[5];
    float* out = (float*)d_out;

    const int M = in_sizes[0] / IN_DIM;   // 50000 nodes
    const int E = in_sizes[1];            // 1,600,000 edges

    // Workspace layout
    ushort* T   = (ushort*)d_ws;                                   // M*128*2 bytes
    size_t  off = (size_t)M * 128 * 2;
    ushort* Wt  = (ushort*)((char*)d_ws + off);                    // 128*136*2 = 34816 B
    off += 128 * 136 * 2;
    int*    rp  = (int*)((char*)d_ws + off);                       // (M+1) ints

    const int nb_rp = (M + 1 + 255) / 256;   // 196
    prep_kernel<<<nb_rp + 16, 256, 0, stream>>>(edst, rp, W, Wt, E, M, nb_rp);

    gemm_kernel<<<(M + 63) / 64, 256, 0, stream>>>(H, Wt, T, M);

    scatter_kernel<<<(M + 3) / 4, 256, 0, stream>>>((const unsigned int*)T, esrc, ew, rp, b, out);
}

// Round 4
// 152.345 us; speedup vs baseline: 1.5723x; 1.0545x over previous
//
#include <hip/hip_runtime.h>

#define IN_DIM 128
#define OUT_DIM 128

typedef __attribute__((ext_vector_type(8))) short short8v;   // 8 bf16 = 4 VGPRs
typedef __attribute__((ext_vector_type(4))) short short4v;   // 4 bf16 = 2 VGPRs
typedef __attribute__((ext_vector_type(4))) float float4v;
typedef __attribute__((ext_vector_type(4))) unsigned int uint4v;

__device__ __forceinline__ ushort f2bf(float f) {
    unsigned int u = __builtin_bit_cast(unsigned int, f);
    unsigned int r = (u + 0x7fffu + ((u >> 16) & 1u)) >> 16;   // RNE
    return (ushort)r;
}

// pack two f32 -> two bf16 in one dword (HW cvt_pk on gfx950 if available)
__device__ __forceinline__ unsigned int pk2bf(float x, float y) {
#if __has_builtin(__builtin_amdgcn_cvt_pk_bf16_f32)
    typedef __attribute__((ext_vector_type(2))) __bf16 bf2;
    bf2 r = __builtin_amdgcn_cvt_pk_bf16_f32(x, y);
    return __builtin_bit_cast(unsigned int, r);
#else
    return (unsigned int)f2bf(x) | ((unsigned int)f2bf(y) << 16);
#endif
}

__device__ __forceinline__ float bflo(unsigned int v) {
    return __builtin_bit_cast(float, v << 16);
}
__device__ __forceinline__ float bfhi(unsigned int v) {
    return __builtin_bit_cast(float, v & 0xffff0000u);
}

// ---------------- Kernel 0: prep ----------------
// blocks [0, nb_rp): row_ptr[n] = lower_bound(edst, n)     (edst sorted)
// blocks [nb_rp, nb_rp+16): Wt[n][k] = bf16(W[k][n]), row stride 136.
// Wt part: coalesced fp32 reads (lanes n-consecutive), packed b32 stores.
__global__ __launch_bounds__(256) void prep_kernel(const int* __restrict__ edst,
                                                   int* __restrict__ rp,
                                                   const float* __restrict__ W,
                                                   ushort* __restrict__ Wt,
                                                   int E, int N, int nb_rp) {
    int bid = blockIdx.x;
    if (bid < nb_rp) {
        int n = bid * 256 + threadIdx.x;
        if (n <= N) {
            int lo = 0, hi = E;
            while (lo < hi) {
                int mid = (lo + hi) >> 1;
                if (edst[mid] < n) lo = mid + 1; else hi = mid;
            }
            rp[n] = lo;
        }
    } else {
        int k0 = (bid - nb_rp) * 8;
        int n = threadIdx.x & 127;
        int half = threadIdx.x >> 7;
#pragma unroll
        for (int kp = 0; kp < 2; ++kp) {
            int k = k0 + (half * 2 + kp) * 2;
            float v0 = W[k * 128 + n];          // coalesced across lanes
            float v1 = W[(k + 1) * 128 + n];
            *(unsigned int*)&Wt[n * 136 + k] = pk2bf(v0, v1);
        }
    }
}

// ---------------- Kernel 1: T(bf16) = H @ W via MFMA ----------------
// Block 256 thr = 4 waves; 64-row x 128-col tile, K=128 unrolled.
// A-frag = Wt rows (K-contiguous, from LDS); B-frag = H rows (K-contiguous,
// loaded DIRECTLY global->reg: lane's 8 fp32 at H[gr*128 + ks*32 + kq]).
// D[n][m] C-layout: lane holds 4 consecutive n of one output row m.
__global__ __launch_bounds__(256) void gemm_kernel(const float* __restrict__ H,
                                                   const ushort* __restrict__ Wt_g,
                                                   ushort* __restrict__ T, int M) {
    __shared__ ushort Ws[128 * 136];   // 34816 B

    const int t = threadIdx.x;
    const int row0 = blockIdx.x * 64;

    // Stage Ws: flat b128 copy (pad bytes copied too, never read by frags)
#pragma unroll
    for (int f = t; f < 2176; f += 256)
        ((short8v*)Ws)[f] = ((const short8v*)Wt_g)[f];

    const int w = t >> 6;
    const int l = t & 63;
    const int m16 = l & 15;
    const int kq = (l >> 4) * 8;
    const int gr = row0 + w * 16 + m16;

    // H fragments: 8 x dwordx4 in flight, then convert
    float4 h[8];
    if (gr < M) {
#pragma unroll
        for (int ks = 0; ks < 4; ++ks) {
            h[ks * 2]     = *(const float4*)&H[gr * 128 + ks * 32 + kq];
            h[ks * 2 + 1] = *(const float4*)&H[gr * 128 + ks * 32 + kq + 4];
        }
    } else {
#pragma unroll
        for (int i = 0; i < 8; ++i) h[i] = make_float4(0.f, 0.f, 0.f, 0.f);
    }

    short8v bfrag[4];
#pragma unroll
    for (int ks = 0; ks < 4; ++ks) {
        uint4v u;
        u[0] = pk2bf(h[ks * 2].x, h[ks * 2].y);
        u[1] = pk2bf(h[ks * 2].z, h[ks * 2].w);
        u[2] = pk2bf(h[ks * 2 + 1].x, h[ks * 2 + 1].y);
        u[3] = pk2bf(h[ks * 2 + 1].z, h[ks * 2 + 1].w);
        bfrag[ks] = __builtin_bit_cast(short8v, u);
    }

    __syncthreads();   // Ws ready

    float4v acc[8];
#pragma unroll
    for (int nt = 0; nt < 8; ++nt) acc[nt] = (float4v){0.f, 0.f, 0.f, 0.f};

#pragma unroll
    for (int ks = 0; ks < 4; ++ks) {
#pragma unroll
        for (int nt = 0; nt < 8; ++nt) {
            short8v afrag = *(const short8v*)&Ws[(nt * 16 + m16) * 136 + ks * 32 + kq];
            acc[nt] = __builtin_amdgcn_mfma_f32_16x16x32_bf16(afrag, bfrag[ks], acc[nt], 0, 0, 0);
        }
    }

    if (gr < M) {
        const int q4 = (l >> 4) * 4;
#pragma unroll
        for (int nt = 0; nt < 8; ++nt) {
            unsigned int p0 = pk2bf(acc[nt][0], acc[nt][1]);
            unsigned int p1 = pk2bf(acc[nt][2], acc[nt][3]);
            uint2 o = make_uint2(p0, p1);
            *(uint2*)&T[gr * 128 + nt * 16 + q4] = o;   // 8 B aligned
        }
    }
}

// ---------------- Kernel 2: out[n][:] = b + sum_{e in seg(n)} w_e * T[src_e][:] ----------------
// One wave per node; lane owns 2 cols (one dword of bf16 T row).
// ILP-8: 8 readlane-broadcast metas + 8 gathers issued before the FMA pass.
// Tail via weight-0 trick: inactive lanes carry srcl=0, wl=0 -> harmless
// row-0 gather with zero weight. No atomics, direct float2 store.
__global__ __launch_bounds__(256) void scatter_kernel(const unsigned int* __restrict__ T2,
                                                      const int* __restrict__ esrc,
                                                      const float* __restrict__ ew,
                                                      const int* __restrict__ rp,
                                                      const float* __restrict__ b,
                                                      float* __restrict__ out) {
    const int node = blockIdx.x * 4 + (threadIdx.x >> 6);
    const int lane = threadIdx.x & 63;

    const int s = rp[node];
    const int e = rp[node + 1];

    float2 bias = *(const float2*)&b[lane * 2];
    float ax = bias.x, ay = bias.y;

    for (int c = s; c < e; c += 64) {
        int idx = c + lane;
        int srcl = 0;
        float wl = 0.f;
        if (idx < e) { srcl = esrc[idx]; wl = ew[idx]; }
        int wli = __builtin_bit_cast(int, wl);
        int nn = e - c;
        if (nn > 64) nn = 64;

        for (int j = 0; j < nn; j += 8) {
            int ss[8];
            float ww[8];
            unsigned int vv[8];
#pragma unroll
            for (int q = 0; q < 8; ++q) {
                ss[q] = __builtin_amdgcn_readlane(srcl, j + q);
                ww[q] = __builtin_bit_cast(float, __builtin_amdgcn_readlane(wli, j + q));
            }
#pragma unroll
            for (int q = 0; q < 8; ++q)
                vv[q] = T2[(unsigned int)ss[q] * 64u + (unsigned int)lane];
#pragma unroll
            for (int q = 0; q < 8; ++q) {
                ax += ww[q] * bflo(vv[q]);
                ay += ww[q] * bfhi(vv[q]);
            }
        }
    }

    *(float2*)&out[node * 128 + lane * 2] = make_float2(ax, ay);
}

extern "C" void kernel_launch(void* const* d_in, const int* in_sizes, int n_in,
                              void* d_out, int out_size, void* d_ws, size_t ws_size,
                              hipStream_t stream) {
    const float* H    = (const float*)d_in[0];
    const int*   esrc = (const int*)d_in[1];
    const int*   edst = (const int*)d_in[2];
    const float* ew   = (const float*)d_in[3];
    const float* W    = (const float*)d_in[4];
    const float* b    = (const float*)d_in[5];
    float* out = (float*)d_out;

    const int M = in_sizes[0] / IN_DIM;   // 50000 nodes
    const int E = in_sizes[1];            // 1,600,000 edges

    // Workspace layout
    ushort* T   = (ushort*)d_ws;                                   // M*128*2 bytes
    size_t  off = (size_t)M * 128 * 2;
    ushort* Wt  = (ushort*)((char*)d_ws + off);                    // 128*136*2 = 34816 B
    off += 128 * 136 * 2;
    int*    rp  = (int*)((char*)d_ws + off);                       // (M+1) ints

    const int nb_rp = (M + 1 + 255) / 256;   // 196
    prep_kernel<<<nb_rp + 16, 256, 0, stream>>>(edst, rp, W, Wt, E, M, nb_rp);

    gemm_kernel<<<(M + 63) / 64, 256, 0, stream>>>(H, Wt, T, M);

    scatter_kernel<<<(M + 3) / 4, 256, 0, stream>>>((const unsigned int*)T, esrc, ew, rp, b, out);
}